// Round 11
// baseline (183.822 us; speedup 1.0000x reference)
//
#include <hip/hip_runtime.h>

// Graph transformer conv on MI355X. N=100000, E=1.6M, DIM=64, H=4, D=8.
// Round 11: minimal bin. Fixed-stride bucket segments let each edge compute
// its global destination directly (LDS hist -> one global atomic per
// (tile,bucket) -> direct scatter). No scan, no LDS staging, no copy-out:
// 2 barriers, 8KB LDS. Writes cluster per bucket segment (L2/L3 absorb).
// sort_aggregate: at its compulsory-gather floor (~165MB @ ~1.8TB/s,
// 6 configs pinned at 103-105us) - unchanged from round 10.

#define NDIM 64
#define NBMAX 1024      // bucket id range (s>>7 < 1024 for N=100K)
#define CTILE 8192
#define STGMAX 4352     // per-bucket capacity (mean 2046, 50-sigma safe)
#define GEMM_BLKS 316   // 196 bin + 316 gemm = 512 blocks = 2/CU exactly

static __device__ __forceinline__ unsigned short f2bf(float f) {
    unsigned int u = __float_as_uint(f);
    unsigned int r = (u + 0x7fffu + ((u >> 16) & 1u)) >> 16;  // RNE
    return (unsigned short)r;
}
static __device__ __forceinline__ float bflo(unsigned int u) {
    return __uint_as_float(u << 16);
}
static __device__ __forceinline__ float bfhi(unsigned int u) {
    return __uint_as_float(u & 0xffff0000u);
}

// ---- 1. fused bin + qkv GEMM (block-range split) -----------------------
__global__ void fused_bin_gemm_kernel(const int* __restrict__ s_arr,
                                      const int* __restrict__ t_arr,
                                      unsigned int* __restrict__ gcur,
                                      unsigned int* __restrict__ binned,
                                      const float* __restrict__ x,
                                      const float* __restrict__ W,
                                      const float* __restrict__ bvec,
                                      unsigned short* __restrict__ qs16,
                                      unsigned short* __restrict__ kv,
                                      int N, int E, int nbin) {
    __shared__ unsigned int sm[2048];     // 8 KB
    int tid = threadIdx.x;

    if (blockIdx.x < (unsigned)nbin) {
        // ---------------- bin path: hist -> reserve -> direct scatter ----
        unsigned int* hist  = sm;         // [1024]
        unsigned int* gbase = sm + 1024;  // [1024] running global cursor
        int e0 = blockIdx.x * CTILE;
        int cnt = min(CTILE, E - e0);

        hist[tid] = 0;
        __syncthreads();
        for (int i = tid; i < cnt; i += 1024)
            atomicAdd(&hist[(unsigned)s_arr[e0 + i] >> 7], 1u);
        __syncthreads();
        {
            unsigned int h = hist[tid];
            gbase[tid] = h
                ? (unsigned)tid * STGMAX + atomicAdd(&gcur[tid], h)
                : 0u;
        }
        __syncthreads();
        for (int i = tid; i < cnt; i += 1024) {
            int s = s_arr[e0 + i];
            int t = t_arr[e0 + i];
            unsigned int bkt = (unsigned)s >> 7;
            unsigned int dst = atomicAdd(&gbase[bkt], 1u);
            if (dst < (bkt + 1u) * STGMAX)          // overflow guard
                binned[dst] = ((unsigned)(s & 127) << 17) | (unsigned)t;
        }
    } else {
        // ---------------- gemm path ----------------
        float4* xs = (float4*)sm;             // [8][16]
        int bid = blockIdx.x - nbin;
        int col = tid & 127;
        int rw  = tid >> 7;                   // 0..7
        float w[64];
        #pragma unroll
        for (int k = 0; k < 64; ++k) w[k] = W[k * 128 + col];
        float bias = bvec[col];

        for (int r0 = bid * 8; r0 < N; r0 += GEMM_BLKS * 8) {
            __syncthreads();
            if (tid < 128) {
                int rr = tid >> 4;
                int cc = tid & 15;
                int n = r0 + rr;
                xs[rr * 16 + cc] = (n < N)
                    ? reinterpret_cast<const float4*>(x)[(size_t)n * 16 + cc]
                    : make_float4(0.f, 0.f, 0.f, 0.f);
            }
            __syncthreads();
            int n = r0 + rw;
            if (n < N) {
                float acc = bias;
                #pragma unroll
                for (int k4 = 0; k4 < 16; ++k4) {
                    float4 xv = xs[rw * 16 + k4];
                    acc = fmaf(xv.x, w[4 * k4 + 0], acc);
                    acc = fmaf(xv.y, w[4 * k4 + 1], acc);
                    acc = fmaf(xv.z, w[4 * k4 + 2], acc);
                    acc = fmaf(xv.w, w[4 * k4 + 3], acc);
                }
                if (col < 32) {
                    qs16[(size_t)n * 32 + col] = f2bf(acc);   // q bf16, unscaled
                } else if (col < 64) {
                    kv[(size_t)n * 96 + (col - 32)] = f2bf(acc);
                } else {
                    kv[(size_t)n * 96 + 32 + (col - 64)] = f2bf(acc);
                }
            }
        }
    }
}

// ---- 2. fused per-bucket sort + aggregate, shuffle-free (round 10) -----
__global__ void __launch_bounds__(512, 8)
sort_aggregate_kernel(const unsigned int* __restrict__ gcur,
                      const unsigned int* __restrict__ binned,
                      const unsigned short* __restrict__ qs16,
                      const unsigned int* __restrict__ kv32,
                      float* __restrict__ out, int N) {
    __shared__ unsigned int hist[128];
    __shared__ unsigned int rstart[128];
    __shared__ unsigned int cur[128];
    __shared__ unsigned int sh[128];
    __shared__ unsigned int stg[STGMAX];

    int b = blockIdx.x;
    int tid = threadIdx.x;
    unsigned int base = (unsigned)b * STGMAX;
    unsigned int cnt = min(gcur[b], (unsigned int)STGMAX);

    if (tid < 128) hist[tid] = 0;
    __syncthreads();
    for (unsigned int i = tid; i < cnt; i += 512)
        atomicAdd(&hist[binned[base + i] >> 17], 1u);
    __syncthreads();

    unsigned int v = (tid < 128) ? hist[tid] : 0;
    unsigned int acc = v;
    if (tid < 128) sh[tid] = acc;
    __syncthreads();
    for (int o = 1; o < 128; o <<= 1) {
        unsigned int add = (tid >= o && tid < 128) ? sh[tid - o] : 0;
        __syncthreads();
        if (tid < 128) { acc += add; sh[tid] = acc; }
        __syncthreads();
    }
    if (tid < 128) {
        unsigned int exc = acc - v;
        rstart[tid] = exc;
        cur[tid] = exc;
    }
    __syncthreads();

    for (unsigned int i = tid; i < cnt; i += 512) {
        unsigned int e = binned[base + i];
        unsigned int p = atomicAdd(&cur[e >> 17], 1u);
        stg[p] = (e & 0x1FFFFu) * 192u;     // byte offset into kv table
    }
    __syncthreads();

    int wid = tid >> 6, lane = tid & 63;
    int hl   = lane & 31;          // v-pair owner: comps 2hl, 2hl+1
    int sub  = lane >> 5;          // which edge of the pair
    int head = hl >> 3;            // 0..3
    const char* kvb = (const char*)kv32;
    const char* qsb = (const char*)qs16;

    for (int nl = wid * 16; nl < wid * 16 + 16; ++nl) {
        int n = b * 128 + nl;
        if (n >= N) break;
        int dg = (int)hist[nl];
        if (dg == 0) {
            if (lane < 32)
                *reinterpret_cast<float2*>(&out[(size_t)n * 64 + 2 * hl]) =
                    make_float2(0.f, 0.f);
            continue;
        }
        int start = (int)rstart[nl];
        int last = start + dg - 1;
        float sc = 0.25f * rsqrtf((float)dg);

        uint4 q4 = *(const uint4*)(qsb + (size_t)n * 64 + (head << 4));
        float qf0 = bflo(q4.x) * sc, qf1 = bfhi(q4.x) * sc;
        float qf2 = bflo(q4.y) * sc, qf3 = bfhi(q4.y) * sc;
        float qf4 = bflo(q4.z) * sc, qf5 = bfhi(q4.z) * sc;
        float qf6 = bflo(q4.w) * sc, qf7 = bfhi(q4.w) * sc;

        float accx = 0.f, accy = 0.f, den = 0.f;
        int npairs = (dg + 1) >> 1;
        int idx = start + sub;

        unsigned int co = stg[min(idx, last)];
        float wm = (idx <= last) ? 1.f : 0.f;
        uint4 kr = *(const uint4*)(kvb + co + (head << 4));
        unsigned int vr = *(const unsigned int*)(kvb + co + 64 + (hl << 2));

        for (int i = 0; i < npairs; ++i) {
            uint4 kr2 = kr; unsigned int vr2 = vr; float wm2 = 0.f;
            int idx2 = idx + 2;
            if (i + 1 < npairs) {
                unsigned int co2 = stg[min(idx2, last)];
                wm2 = (idx2 <= last) ? 1.f : 0.f;
                kr2 = *(const uint4*)(kvb + co2 + (head << 4));
                vr2 = *(const unsigned int*)(kvb + co2 + 64 + (hl << 2));
            }
            float p = qf0 * bflo(kr.x);
            p = fmaf(qf1, bfhi(kr.x), p);
            p = fmaf(qf2, bflo(kr.y), p);
            p = fmaf(qf3, bfhi(kr.y), p);
            p = fmaf(qf4, bflo(kr.z), p);
            p = fmaf(qf5, bfhi(kr.z), p);
            p = fmaf(qf6, bflo(kr.w), p);
            p = fmaf(qf7, bfhi(kr.w), p);
            float w = __expf(p) * wm;
            accx = fmaf(w, bflo(vr), accx);
            accy = fmaf(w, bfhi(vr), accy);
            den += w;
            kr = kr2; vr = vr2; wm = wm2; idx = idx2;
        }

        accx += __shfl_xor(accx, 32);
        accy += __shfl_xor(accy, 32);
        den  += __shfl_xor(den, 32);

        if (lane < 32) {
            float inv = 1.0f / (den + 1e-16f);
            *reinterpret_cast<float2*>(&out[(size_t)n * 64 + 2 * hl]) =
                make_float2(accx * inv, accy * inv);
        }
    }
}

extern "C" void kernel_launch(void* const* d_in, const int* in_sizes, int n_in,
                              void* d_out, int out_size, void* d_ws, size_t ws_size,
                              hipStream_t stream) {
    const float* x = (const float*)d_in[0];
    const int*   eidx = (const int*)d_in[1];
    const float* W = (const float*)d_in[2];
    const float* b = (const float*)d_in[3];
    int N = in_sizes[0] / NDIM;
    int E = in_sizes[1] / 2;
    float* out = (float*)d_out;

    int NB = (N + 127) / 128;                  // 782 buckets
    int nbin = (E + CTILE - 1) / CTILE;        // 196 bin tiles

    // workspace layout
    unsigned short* qs16 = (unsigned short*)d_ws;                 // N*32 u16
    unsigned short* kv = qs16 + (size_t)N * 32;                   // N*96 u16
    unsigned int* gcur = (unsigned int*)(kv + (size_t)N * 96);    // NBMAX
    unsigned int* binned = gcur + NBMAX;       // NB*STGMAX u32 (~13.6 MB)

    const int* s_arr = eidx;
    const int* t_arr = eidx + E;

    hipMemsetAsync(gcur, 0, NBMAX * sizeof(unsigned int), stream);

    fused_bin_gemm_kernel<<<nbin + GEMM_BLKS, 1024, 0, stream>>>(
        s_arr, t_arr, gcur, binned, x, W, b, qs16, kv, N, E, nbin);
    sort_aggregate_kernel<<<NB, 512, 0, stream>>>(
        gcur, binned, qs16, (const unsigned int*)kv, out, N);
}

// Round 12
// 182.064 us; speedup vs baseline: 1.0097x; 1.0097x over previous
//
#include <hip/hip_runtime.h>

// Graph transformer conv on MI355X. N=100000, E=1.6M, DIM=64, H=4, D=8.
// Round 12: round-10 structure (LDS-staged bin + coalesced segment copy-out,
// fixed-stride segments, shuffle-free gather) with the barrier-heavy
// Hillis-Steele scans replaced by wave-shuffle scans (bin: 20->3 barriers,
// sort_agg: 14->2). sort_aggregate gather loop untouched (at its compulsory
// ~165MB @ ~1.8TB/s floor across 7 configs).

#define NDIM 64
#define NBMAX 1024      // bucket id range (s>>7 < 1024 for N=100K)
#define CTILE 8192
#define STGMAX 4352     // per-bucket capacity (mean 2046, 50-sigma safe)
#define GEMM_BLKS 316   // 196 bin + 316 gemm = 512 blocks = 2/CU exactly

static __device__ __forceinline__ unsigned short f2bf(float f) {
    unsigned int u = __float_as_uint(f);
    unsigned int r = (u + 0x7fffu + ((u >> 16) & 1u)) >> 16;  // RNE
    return (unsigned short)r;
}
static __device__ __forceinline__ float bflo(unsigned int u) {
    return __uint_as_float(u << 16);
}
static __device__ __forceinline__ float bfhi(unsigned int u) {
    return __uint_as_float(u & 0xffff0000u);
}

// ---- 1. fused bin + qkv GEMM (block-range split) -----------------------
__global__ void fused_bin_gemm_kernel(const int* __restrict__ s_arr,
                                      const int* __restrict__ t_arr,
                                      unsigned int* __restrict__ gcur,
                                      unsigned int* __restrict__ binned,
                                      const float* __restrict__ x,
                                      const float* __restrict__ W,
                                      const float* __restrict__ bvec,
                                      unsigned short* __restrict__ qs16,
                                      unsigned short* __restrict__ kv,
                                      int N, int E, int nbin) {
    __shared__ unsigned int sm[12288];    // 48 KB
    unsigned int* hist  = sm;             // [1024]
    unsigned int* off   = sm + 1024;      // [1024]
    unsigned int* gbase = sm + 2048;      // [1024]
    unsigned int* psum  = sm + 3072;      // [1024] inclusive scan
    unsigned int* stg   = sm + 4096;      // [8192]
    int tid = threadIdx.x;

    if (blockIdx.x < (unsigned)nbin) {
        // ---------------- bin path ----------------
        int e0 = blockIdx.x * CTILE;
        int cnt = min(CTILE, E - e0);
        int lane = tid & 63, wid = tid >> 6;

        hist[tid] = 0;
        __syncthreads();
        for (int i = tid; i < cnt; i += 1024)
            atomicAdd(&hist[(unsigned)s_arr[e0 + i] >> 7], 1u);
        __syncthreads();

        // wave-shuffle scan of hist[1024]: 3 barriers total
        unsigned int v_in = hist[tid];
        unsigned int v = v_in;
        #pragma unroll
        for (int d = 1; d < 64; d <<= 1) {
            unsigned int o = __shfl_up(v, d);
            if (lane >= d) v += o;
        }
        if (lane == 63) gbase[wid] = v;       // reuse gbase[0..15] as wave sums
        __syncthreads();
        if (tid < 16) {
            unsigned int w0 = gbase[tid];
            unsigned int wv = w0;
            #pragma unroll
            for (int d = 1; d < 16; d <<= 1) {
                unsigned int o = __shfl_up(wv, d);
                if (tid >= d) wv += o;
            }
            gbase[tid] = wv - w0;             // exclusive wave offset
        }
        __syncthreads();
        unsigned int incl = v + gbase[wid];
        psum[tid] = incl;
        off[tid] = incl - v_in;
        __syncthreads();

        for (int i = tid; i < cnt; i += 1024) {
            int s = s_arr[e0 + i];
            int t = t_arr[e0 + i];
            unsigned int bkt = (unsigned)s >> 7;
            unsigned int p = atomicAdd(&off[bkt], 1u);
            stg[p] = ((unsigned)(s & 127) << 17) | (unsigned)t;
        }
        __syncthreads();

        // reserve fixed-stride global segment per bucket (clamped)
        {
            unsigned int h = hist[tid];
            unsigned int resv = h ? atomicAdd(&gcur[tid], h) : 0u;
            unsigned int m = (resv < STGMAX) ? min(h, STGMAX - resv) : 0u;
            hist[tid] = m;
            gbase[tid] = (unsigned)tid * STGMAX + resv;
        }
        __syncthreads();

        for (int b = wid; b < NBMAX; b += 16) {
            unsigned int m = hist[b];
            if (m == 0) continue;
            unsigned int start = (b > 0) ? psum[b - 1] : 0u;
            unsigned int dst = gbase[b];
            for (unsigned int i = lane; i < m; i += 64)
                binned[dst + i] = stg[start + i];
        }
    } else {
        // ---------------- gemm path ----------------
        float4* xs = (float4*)sm;             // [8][16]
        int bid = blockIdx.x - nbin;
        int col = tid & 127;
        int rw  = tid >> 7;                   // 0..7
        float w[64];
        #pragma unroll
        for (int k = 0; k < 64; ++k) w[k] = W[k * 128 + col];
        float bias = bvec[col];

        for (int r0 = bid * 8; r0 < N; r0 += GEMM_BLKS * 8) {
            __syncthreads();
            if (tid < 128) {
                int rr = tid >> 4;
                int cc = tid & 15;
                int n = r0 + rr;
                xs[rr * 16 + cc] = (n < N)
                    ? reinterpret_cast<const float4*>(x)[(size_t)n * 16 + cc]
                    : make_float4(0.f, 0.f, 0.f, 0.f);
            }
            __syncthreads();
            int n = r0 + rw;
            if (n < N) {
                float acc = bias;
                #pragma unroll
                for (int k4 = 0; k4 < 16; ++k4) {
                    float4 xv = xs[rw * 16 + k4];
                    acc = fmaf(xv.x, w[4 * k4 + 0], acc);
                    acc = fmaf(xv.y, w[4 * k4 + 1], acc);
                    acc = fmaf(xv.z, w[4 * k4 + 2], acc);
                    acc = fmaf(xv.w, w[4 * k4 + 3], acc);
                }
                if (col < 32) {
                    qs16[(size_t)n * 32 + col] = f2bf(acc);   // q bf16, unscaled
                } else if (col < 64) {
                    kv[(size_t)n * 96 + (col - 32)] = f2bf(acc);
                } else {
                    kv[(size_t)n * 96 + 32 + (col - 64)] = f2bf(acc);
                }
            }
        }
    }
}

// ---- 2. fused per-bucket sort + aggregate, shuffle-free ----------------
__global__ void __launch_bounds__(512, 8)
sort_aggregate_kernel(const unsigned int* __restrict__ gcur,
                      const unsigned int* __restrict__ binned,
                      const unsigned short* __restrict__ qs16,
                      const unsigned int* __restrict__ kv32,
                      float* __restrict__ out, int N) {
    __shared__ unsigned int hist[128];
    __shared__ unsigned int rstart[128];
    __shared__ unsigned int cur[128];
    __shared__ unsigned int wsum[2];
    __shared__ unsigned int stg[STGMAX];

    int b = blockIdx.x;
    int tid = threadIdx.x;
    unsigned int base = (unsigned)b * STGMAX;
    unsigned int cnt = min(gcur[b], (unsigned int)STGMAX);

    if (tid < 128) hist[tid] = 0;
    __syncthreads();
    for (unsigned int i = tid; i < cnt; i += 512)
        atomicAdd(&hist[binned[base + i] >> 17], 1u);
    __syncthreads();

    // wave-shuffle scan of hist[128] (2 barriers)
    {
        int lane = tid & 63, wid = tid >> 6;
        unsigned int v_in = (tid < 128) ? hist[tid] : 0;
        unsigned int v = v_in;
        #pragma unroll
        for (int d = 1; d < 64; d <<= 1) {
            unsigned int o = __shfl_up(v, d);
            if (lane >= d) v += o;
        }
        if (tid < 128 && lane == 63) wsum[wid] = v;
        __syncthreads();
        if (tid < 128) {
            unsigned int incl = v + ((wid == 1) ? wsum[0] : 0u);
            unsigned int exc = incl - v_in;
            rstart[tid] = exc;
            cur[tid] = exc;
        }
        __syncthreads();
    }

    for (unsigned int i = tid; i < cnt; i += 512) {
        unsigned int e = binned[base + i];
        unsigned int p = atomicAdd(&cur[e >> 17], 1u);
        stg[p] = (e & 0x1FFFFu) * 192u;     // byte offset into kv table
    }
    __syncthreads();

    int wid = tid >> 6, lane = tid & 63;
    int hl   = lane & 31;          // v-pair owner: comps 2hl, 2hl+1
    int sub  = lane >> 5;          // which edge of the pair
    int head = hl >> 3;            // 0..3
    const char* kvb = (const char*)kv32;
    const char* qsb = (const char*)qs16;

    for (int nl = wid * 16; nl < wid * 16 + 16; ++nl) {
        int n = b * 128 + nl;
        if (n >= N) break;
        int dg = (int)hist[nl];
        if (dg == 0) {
            if (lane < 32)
                *reinterpret_cast<float2*>(&out[(size_t)n * 64 + 2 * hl]) =
                    make_float2(0.f, 0.f);
            continue;
        }
        int start = (int)rstart[nl];
        int last = start + dg - 1;
        float sc = 0.25f * rsqrtf((float)dg);

        uint4 q4 = *(const uint4*)(qsb + (size_t)n * 64 + (head << 4));
        float qf0 = bflo(q4.x) * sc, qf1 = bfhi(q4.x) * sc;
        float qf2 = bflo(q4.y) * sc, qf3 = bfhi(q4.y) * sc;
        float qf4 = bflo(q4.z) * sc, qf5 = bfhi(q4.z) * sc;
        float qf6 = bflo(q4.w) * sc, qf7 = bfhi(q4.w) * sc;

        float accx = 0.f, accy = 0.f, den = 0.f;
        int npairs = (dg + 1) >> 1;
        int idx = start + sub;

        unsigned int co = stg[min(idx, last)];
        float wm = (idx <= last) ? 1.f : 0.f;
        uint4 kr = *(const uint4*)(kvb + co + (head << 4));
        unsigned int vr = *(const unsigned int*)(kvb + co + 64 + (hl << 2));

        for (int i = 0; i < npairs; ++i) {
            uint4 kr2 = kr; unsigned int vr2 = vr; float wm2 = 0.f;
            int idx2 = idx + 2;
            if (i + 1 < npairs) {
                unsigned int co2 = stg[min(idx2, last)];
                wm2 = (idx2 <= last) ? 1.f : 0.f;
                kr2 = *(const uint4*)(kvb + co2 + (head << 4));
                vr2 = *(const unsigned int*)(kvb + co2 + 64 + (hl << 2));
            }
            float p = qf0 * bflo(kr.x);
            p = fmaf(qf1, bfhi(kr.x), p);
            p = fmaf(qf2, bflo(kr.y), p);
            p = fmaf(qf3, bfhi(kr.y), p);
            p = fmaf(qf4, bflo(kr.z), p);
            p = fmaf(qf5, bfhi(kr.z), p);
            p = fmaf(qf6, bflo(kr.w), p);
            p = fmaf(qf7, bfhi(kr.w), p);
            float w = __expf(p) * wm;
            accx = fmaf(w, bflo(vr), accx);
            accy = fmaf(w, bfhi(vr), accy);
            den += w;
            kr = kr2; vr = vr2; wm = wm2; idx = idx2;
        }

        accx += __shfl_xor(accx, 32);
        accy += __shfl_xor(accy, 32);
        den  += __shfl_xor(den, 32);

        if (lane < 32) {
            float inv = 1.0f / (den + 1e-16f);
            *reinterpret_cast<float2*>(&out[(size_t)n * 64 + 2 * hl]) =
                make_float2(accx * inv, accy * inv);
        }
    }
}

extern "C" void kernel_launch(void* const* d_in, const int* in_sizes, int n_in,
                              void* d_out, int out_size, void* d_ws, size_t ws_size,
                              hipStream_t stream) {
    const float* x = (const float*)d_in[0];
    const int*   eidx = (const int*)d_in[1];
    const float* W = (const float*)d_in[2];
    const float* b = (const float*)d_in[3];
    int N = in_sizes[0] / NDIM;
    int E = in_sizes[1] / 2;
    float* out = (float*)d_out;

    int NB = (N + 127) / 128;                  // 782 buckets
    int nbin = (E + CTILE - 1) / CTILE;        // 196 bin tiles

    // workspace layout
    unsigned short* qs16 = (unsigned short*)d_ws;                 // N*32 u16
    unsigned short* kv = qs16 + (size_t)N * 32;                   // N*96 u16
    unsigned int* gcur = (unsigned int*)(kv + (size_t)N * 96);    // NBMAX
    unsigned int* binned = gcur + NBMAX;       // NB*STGMAX u32 (~13.6 MB)

    const int* s_arr = eidx;
    const int* t_arr = eidx + E;

    hipMemsetAsync(gcur, 0, NBMAX * sizeof(unsigned int), stream);

    fused_bin_gemm_kernel<<<nbin + GEMM_BLKS, 1024, 0, stream>>>(
        s_arr, t_arr, gcur, binned, x, W, b, qs16, kv, N, E, nbin);
    sort_aggregate_kernel<<<NB, 512, 0, stream>>>(
        gcur, binned, qs16, (const unsigned int*)kv, out, N);
}

// Round 13
// 181.398 us; speedup vs baseline: 1.0134x; 1.0037x over previous
//
#include <hip/hip_runtime.h>

// Graph transformer conv on MI355X. N=100000, E=1.6M, DIM=64, H=4, D=8.
// Round 13: XCD-partitioned direct-scatter bin. binned is [8][1024][STGP];
// each bin block writes only partition blockIdx&7 (same-XCD blocks share L2,
// so partial 64B lines accumulate locally - fixes round 11's 7x write amp
// without round 10/12's LDS staging+copy-out). Bin: hist -> 1 reserve atomic
// per bucket -> direct scatter. sort_aggregate drains 8 partitions; gather
// loop untouched (~103us compulsory floor, 7 configs).

#define NDIM 64
#define NBMAX 1024      // bucket id range (s>>7 < 1024 for N=100K)
#define CTILE 8192
#define STGP 384        // per-(bucket,partition) capacity (mean 261, +7.6 sigma)
#define STGTOT 3072     // 8*STGP, max edges per bucket in sort_agg
#define GEMM_BLKS 316   // 196 bin + 316 gemm = 512 blocks = 2/CU

static __device__ __forceinline__ unsigned short f2bf(float f) {
    unsigned int u = __float_as_uint(f);
    unsigned int r = (u + 0x7fffu + ((u >> 16) & 1u)) >> 16;  // RNE
    return (unsigned short)r;
}
static __device__ __forceinline__ float bflo(unsigned int u) {
    return __uint_as_float(u << 16);
}
static __device__ __forceinline__ float bfhi(unsigned int u) {
    return __uint_as_float(u & 0xffff0000u);
}

// ---- 1. fused bin + qkv GEMM (block-range split) -----------------------
__global__ void fused_bin_gemm_kernel(const int* __restrict__ s_arr,
                                      const int* __restrict__ t_arr,
                                      unsigned int* __restrict__ gcur,
                                      unsigned int* __restrict__ binned,
                                      const float* __restrict__ x,
                                      const float* __restrict__ W,
                                      const float* __restrict__ bvec,
                                      unsigned short* __restrict__ qs16,
                                      unsigned short* __restrict__ kv,
                                      int N, int E, int nbin) {
    __shared__ unsigned int sm[2048];     // 8 KB
    int tid = threadIdx.x;

    if (blockIdx.x < (unsigned)nbin) {
        // ---- bin path: hist -> reserve -> XCD-local direct scatter ----
        unsigned int* hist  = sm;         // [1024]
        unsigned int* gbase = sm + 1024;  // [1024] running global cursor
        int e0 = blockIdx.x * CTILE;
        int cnt = min(CTILE, E - e0);
        unsigned int part = blockIdx.x & 7u;   // ~XCD id (round-robin dispatch)

        hist[tid] = 0;
        __syncthreads();
        for (int i = tid; i < cnt; i += 1024)
            atomicAdd(&hist[(unsigned)s_arr[e0 + i] >> 7], 1u);
        __syncthreads();
        {
            unsigned int h = hist[tid];
            unsigned int seg = part * (unsigned)NBMAX + (unsigned)tid;
            gbase[tid] = h
                ? seg * STGP + atomicAdd(&gcur[seg], h)
                : 0u;
        }
        __syncthreads();
        for (int i = tid; i < cnt; i += 1024) {
            int s = s_arr[e0 + i];
            int t = t_arr[e0 + i];
            unsigned int bkt = (unsigned)s >> 7;
            unsigned int dst = atomicAdd(&gbase[bkt], 1u);
            unsigned int lim = (part * (unsigned)NBMAX + bkt + 1u) * STGP;
            if (dst < lim)                       // overflow guard (never hit)
                binned[dst] = ((unsigned)(s & 127) << 17) | (unsigned)t;
        }
    } else {
        // ---------------- gemm path ----------------
        float4* xs = (float4*)sm;             // [8][16]
        int bid = blockIdx.x - nbin;
        int col = tid & 127;
        int rw  = tid >> 7;                   // 0..7
        float w[64];
        #pragma unroll
        for (int k = 0; k < 64; ++k) w[k] = W[k * 128 + col];
        float bias = bvec[col];

        for (int r0 = bid * 8; r0 < N; r0 += GEMM_BLKS * 8) {
            __syncthreads();
            if (tid < 128) {
                int rr = tid >> 4;
                int cc = tid & 15;
                int n = r0 + rr;
                xs[rr * 16 + cc] = (n < N)
                    ? reinterpret_cast<const float4*>(x)[(size_t)n * 16 + cc]
                    : make_float4(0.f, 0.f, 0.f, 0.f);
            }
            __syncthreads();
            int n = r0 + rw;
            if (n < N) {
                float acc = bias;
                #pragma unroll
                for (int k4 = 0; k4 < 16; ++k4) {
                    float4 xv = xs[rw * 16 + k4];
                    acc = fmaf(xv.x, w[4 * k4 + 0], acc);
                    acc = fmaf(xv.y, w[4 * k4 + 1], acc);
                    acc = fmaf(xv.z, w[4 * k4 + 2], acc);
                    acc = fmaf(xv.w, w[4 * k4 + 3], acc);
                }
                if (col < 32) {
                    qs16[(size_t)n * 32 + col] = f2bf(acc);   // q bf16, unscaled
                } else if (col < 64) {
                    kv[(size_t)n * 96 + (col - 32)] = f2bf(acc);
                } else {
                    kv[(size_t)n * 96 + 32 + (col - 64)] = f2bf(acc);
                }
            }
        }
    }
}

// ---- 2. fused per-bucket sort + aggregate, shuffle-free ----------------
__global__ void __launch_bounds__(512, 8)
sort_aggregate_kernel(const unsigned int* __restrict__ gcur,
                      const unsigned int* __restrict__ binned,
                      const unsigned short* __restrict__ qs16,
                      const unsigned int* __restrict__ kv32,
                      float* __restrict__ out, int N) {
    __shared__ unsigned int hist[128];
    __shared__ unsigned int rstart[128];
    __shared__ unsigned int cur[128];
    __shared__ unsigned int wsum[2];
    __shared__ unsigned int stg[STGTOT];

    int b = blockIdx.x;
    int tid = threadIdx.x;

    if (tid < 128) hist[tid] = 0;
    __syncthreads();
    #pragma unroll
    for (int p = 0; p < 8; ++p) {
        unsigned int seg = (unsigned)p * NBMAX + (unsigned)b;
        unsigned int base = seg * STGP;
        unsigned int cnt = min(gcur[seg], (unsigned int)STGP);
        for (unsigned int i = tid; i < cnt; i += 512)
            atomicAdd(&hist[binned[base + i] >> 17], 1u);
    }
    __syncthreads();

    // wave-shuffle scan of hist[128] (2 barriers)
    {
        int lane = tid & 63, wid = tid >> 6;
        unsigned int v_in = (tid < 128) ? hist[tid] : 0;
        unsigned int v = v_in;
        #pragma unroll
        for (int d = 1; d < 64; d <<= 1) {
            unsigned int o = __shfl_up(v, d);
            if (lane >= d) v += o;
        }
        if (tid < 128 && lane == 63) wsum[wid] = v;
        __syncthreads();
        if (tid < 128) {
            unsigned int incl = v + ((wid == 1) ? wsum[0] : 0u);
            unsigned int exc = incl - v_in;
            rstart[tid] = exc;
            cur[tid] = exc;
        }
        __syncthreads();
    }

    #pragma unroll
    for (int p = 0; p < 8; ++p) {
        unsigned int seg = (unsigned)p * NBMAX + (unsigned)b;
        unsigned int base = seg * STGP;
        unsigned int cnt = min(gcur[seg], (unsigned int)STGP);
        for (unsigned int i = tid; i < cnt; i += 512) {
            unsigned int e = binned[base + i];
            unsigned int pp = atomicAdd(&cur[e >> 17], 1u);
            stg[pp] = (e & 0x1FFFFu) * 192u;   // byte offset into kv table
        }
    }
    __syncthreads();

    int wid = tid >> 6, lane = tid & 63;
    int hl   = lane & 31;          // v-pair owner: comps 2hl, 2hl+1
    int sub  = lane >> 5;          // which edge of the pair
    int head = hl >> 3;            // 0..3
    const char* kvb = (const char*)kv32;
    const char* qsb = (const char*)qs16;

    for (int nl = wid * 16; nl < wid * 16 + 16; ++nl) {
        int n = b * 128 + nl;
        if (n >= N) break;
        int dg = (int)hist[nl];
        if (dg == 0) {
            if (lane < 32)
                *reinterpret_cast<float2*>(&out[(size_t)n * 64 + 2 * hl]) =
                    make_float2(0.f, 0.f);
            continue;
        }
        int start = (int)rstart[nl];
        int last = start + dg - 1;
        float sc = 0.25f * rsqrtf((float)dg);

        uint4 q4 = *(const uint4*)(qsb + (size_t)n * 64 + (head << 4));
        float qf0 = bflo(q4.x) * sc, qf1 = bfhi(q4.x) * sc;
        float qf2 = bflo(q4.y) * sc, qf3 = bfhi(q4.y) * sc;
        float qf4 = bflo(q4.z) * sc, qf5 = bfhi(q4.z) * sc;
        float qf6 = bflo(q4.w) * sc, qf7 = bfhi(q4.w) * sc;

        float accx = 0.f, accy = 0.f, den = 0.f;
        int npairs = (dg + 1) >> 1;
        int idx = start + sub;

        unsigned int co = stg[min(idx, last)];
        float wm = (idx <= last) ? 1.f : 0.f;
        uint4 kr = *(const uint4*)(kvb + co + (head << 4));
        unsigned int vr = *(const unsigned int*)(kvb + co + 64 + (hl << 2));

        for (int i = 0; i < npairs; ++i) {
            uint4 kr2 = kr; unsigned int vr2 = vr; float wm2 = 0.f;
            int idx2 = idx + 2;
            if (i + 1 < npairs) {
                unsigned int co2 = stg[min(idx2, last)];
                wm2 = (idx2 <= last) ? 1.f : 0.f;
                kr2 = *(const uint4*)(kvb + co2 + (head << 4));
                vr2 = *(const unsigned int*)(kvb + co2 + 64 + (hl << 2));
            }
            float p = qf0 * bflo(kr.x);
            p = fmaf(qf1, bfhi(kr.x), p);
            p = fmaf(qf2, bflo(kr.y), p);
            p = fmaf(qf3, bfhi(kr.y), p);
            p = fmaf(qf4, bflo(kr.z), p);
            p = fmaf(qf5, bfhi(kr.z), p);
            p = fmaf(qf6, bflo(kr.w), p);
            p = fmaf(qf7, bfhi(kr.w), p);
            float w = __expf(p) * wm;
            accx = fmaf(w, bflo(vr), accx);
            accy = fmaf(w, bfhi(vr), accy);
            den += w;
            kr = kr2; vr = vr2; wm = wm2; idx = idx2;
        }

        accx += __shfl_xor(accx, 32);
        accy += __shfl_xor(accy, 32);
        den  += __shfl_xor(den, 32);

        if (lane < 32) {
            float inv = 1.0f / (den + 1e-16f);
            *reinterpret_cast<float2*>(&out[(size_t)n * 64 + 2 * hl]) =
                make_float2(accx * inv, accy * inv);
        }
    }
}

extern "C" void kernel_launch(void* const* d_in, const int* in_sizes, int n_in,
                              void* d_out, int out_size, void* d_ws, size_t ws_size,
                              hipStream_t stream) {
    const float* x = (const float*)d_in[0];
    const int*   eidx = (const int*)d_in[1];
    const float* W = (const float*)d_in[2];
    const float* b = (const float*)d_in[3];
    int N = in_sizes[0] / NDIM;
    int E = in_sizes[1] / 2;
    float* out = (float*)d_out;

    int NB = (N + 127) / 128;                  // 782 buckets
    int nbin = (E + CTILE - 1) / CTILE;        // 196 bin tiles

    // workspace layout
    unsigned short* qs16 = (unsigned short*)d_ws;                 // N*32 u16
    unsigned short* kv = qs16 + (size_t)N * 32;                   // N*96 u16
    unsigned int* gcur = (unsigned int*)(kv + (size_t)N * 96);    // 8*NBMAX
    unsigned int* binned = gcur + 8 * NBMAX;   // 8*NBMAX*STGP u32 (~12.6 MB)

    const int* s_arr = eidx;
    const int* t_arr = eidx + E;

    hipMemsetAsync(gcur, 0, 8 * NBMAX * sizeof(unsigned int), stream);

    fused_bin_gemm_kernel<<<nbin + GEMM_BLKS, 1024, 0, stream>>>(
        s_arr, t_arr, gcur, binned, x, W, b, qs16, kv, N, E, nbin);
    sort_aggregate_kernel<<<NB, 512, 0, stream>>>(
        gcur, binned, qs16, (const unsigned int*)kv, out, N);
}

// Round 14
// 171.924 us; speedup vs baseline: 1.0692x; 1.0551x over previous
//
#include <hip/hip_runtime.h>

// Graph transformer conv on MI355X. N=100000, E=1.6M, DIM=64, H=4, D=8.
// Round 14: revert to round-10 configuration (best measured: 171.1 us).
// - sort_aggregate: at compulsory gather floor. FETCH ~165MB = 8 XCDs x
//   19.2MB kv table (+binned/qs), served at ~1.8 TB/s line-fill rate;
//   invariant across 7 inner-loop structures (MLP/TLP/shuffle-free).
// - prep (fused bin+GEMM): ~65us best of 4 variants (staged copy-out wins:
//   direct scatter ping-pongs partial lines cross-XCD (r11, 7x write amp);
//   XCD-partitioned direct is clean but slower (r13); barriers not the
//   bottleneck (r12 wave-scan neutral)).

#define NDIM 64
#define NBMAX 1024      // bucket id range (s>>7 < 1024 for N=100K)
#define CTILE 8192
#define STGMAX 4352     // per-bucket capacity (mean 2046, 50-sigma safe)
#define GEMM_BLKS 256

static __device__ __forceinline__ unsigned short f2bf(float f) {
    unsigned int u = __float_as_uint(f);
    unsigned int r = (u + 0x7fffu + ((u >> 16) & 1u)) >> 16;  // RNE
    return (unsigned short)r;
}
static __device__ __forceinline__ float bflo(unsigned int u) {
    return __uint_as_float(u << 16);
}
static __device__ __forceinline__ float bfhi(unsigned int u) {
    return __uint_as_float(u & 0xffff0000u);
}

// ---- 1. fused bin + qkv GEMM (independent work, block-range split) -----
__global__ void fused_bin_gemm_kernel(const int* __restrict__ s_arr,
                                      const int* __restrict__ t_arr,
                                      unsigned int* __restrict__ gcur,
                                      unsigned int* __restrict__ binned,
                                      const float* __restrict__ x,
                                      const float* __restrict__ W,
                                      const float* __restrict__ bvec,
                                      unsigned short* __restrict__ qs16,
                                      unsigned short* __restrict__ kv,
                                      int N, int E, int nbin) {
    __shared__ unsigned int sm[12288];    // 48 KB
    unsigned int* hist  = sm;             // [1024]
    unsigned int* off   = sm + 1024;      // [1024]
    unsigned int* gbase = sm + 2048;      // [1024]
    unsigned int* psum  = sm + 3072;      // [1024]
    unsigned int* stg   = sm + 4096;      // [8192]
    int tid = threadIdx.x;

    if (blockIdx.x < (unsigned)nbin) {
        // ---------------- bin path ----------------
        int e0 = blockIdx.x * CTILE;
        int cnt = min(CTILE, E - e0);

        hist[tid] = 0;
        __syncthreads();
        for (int i = tid; i < cnt; i += 1024)
            atomicAdd(&hist[(unsigned)s_arr[e0 + i] >> 7], 1u);
        __syncthreads();

        // exclusive scan of hist[1024] (Hillis-Steele, psum ends inclusive)
        unsigned int v = hist[tid];
        unsigned int acc = v;
        psum[tid] = acc;
        __syncthreads();
        for (int o = 1; o < 1024; o <<= 1) {
            unsigned int add = (tid >= o) ? psum[tid - o] : 0;
            __syncthreads();
            acc += add;
            psum[tid] = acc;
            __syncthreads();
        }
        off[tid] = acc - v;
        __syncthreads();

        for (int i = tid; i < cnt; i += 1024) {
            int s = s_arr[e0 + i];
            int t = t_arr[e0 + i];
            unsigned int bkt = (unsigned)s >> 7;
            unsigned int p = atomicAdd(&off[bkt], 1u);
            stg[p] = ((unsigned)(s & 127) << 17) | (unsigned)t;
        }
        __syncthreads();

        // reserve fixed-stride global segment per bucket (clamped)
        {
            unsigned int h = hist[tid];
            unsigned int resv = h ? atomicAdd(&gcur[tid], h) : 0u;
            unsigned int m = (resv < STGMAX) ? min(h, STGMAX - resv) : 0u;
            hist[tid] = m;
            gbase[tid] = (unsigned)tid * STGMAX + resv;
        }
        __syncthreads();

        int wid = tid >> 6, lane = tid & 63;
        for (int b = wid; b < NBMAX; b += 16) {
            unsigned int m = hist[b];
            if (m == 0) continue;
            unsigned int start = (b > 0) ? psum[b - 1] : 0u;
            unsigned int dst = gbase[b];
            for (unsigned int i = lane; i < m; i += 64)
                binned[dst + i] = stg[start + i];
        }
    } else {
        // ---------------- gemm path ----------------
        float4* xs = (float4*)sm;             // [8][16]
        int bid = blockIdx.x - nbin;
        int col = tid & 127;
        int rw  = tid >> 7;                   // 0..7
        float w[64];
        #pragma unroll
        for (int k = 0; k < 64; ++k) w[k] = W[k * 128 + col];
        float bias = bvec[col];

        for (int r0 = bid * 8; r0 < N; r0 += GEMM_BLKS * 8) {
            __syncthreads();
            if (tid < 128) {
                int rr = tid >> 4;
                int cc = tid & 15;
                int n = r0 + rr;
                xs[rr * 16 + cc] = (n < N)
                    ? reinterpret_cast<const float4*>(x)[(size_t)n * 16 + cc]
                    : make_float4(0.f, 0.f, 0.f, 0.f);
            }
            __syncthreads();
            int n = r0 + rw;
            if (n < N) {
                float acc = bias;
                #pragma unroll
                for (int k4 = 0; k4 < 16; ++k4) {
                    float4 xv = xs[rw * 16 + k4];
                    acc = fmaf(xv.x, w[4 * k4 + 0], acc);
                    acc = fmaf(xv.y, w[4 * k4 + 1], acc);
                    acc = fmaf(xv.z, w[4 * k4 + 2], acc);
                    acc = fmaf(xv.w, w[4 * k4 + 3], acc);
                }
                if (col < 32) {
                    qs16[(size_t)n * 32 + col] = f2bf(acc);   // q bf16, unscaled
                } else if (col < 64) {
                    kv[(size_t)n * 96 + (col - 32)] = f2bf(acc);
                } else {
                    kv[(size_t)n * 96 + 32 + (col - 64)] = f2bf(acc);
                }
            }
        }
    }
}

// ---- 2. fused per-bucket sort + aggregate, shuffle-free ----------------
__global__ void __launch_bounds__(512, 8)
sort_aggregate_kernel(const unsigned int* __restrict__ gcur,
                      const unsigned int* __restrict__ binned,
                      const unsigned short* __restrict__ qs16,
                      const unsigned int* __restrict__ kv32,
                      float* __restrict__ out, int N) {
    __shared__ unsigned int hist[128];
    __shared__ unsigned int rstart[128];
    __shared__ unsigned int cur[128];
    __shared__ unsigned int sh[128];
    __shared__ unsigned int stg[STGMAX];

    int b = blockIdx.x;
    int tid = threadIdx.x;
    unsigned int base = (unsigned)b * STGMAX;
    unsigned int cnt = min(gcur[b], (unsigned int)STGMAX);

    if (tid < 128) hist[tid] = 0;
    __syncthreads();
    for (unsigned int i = tid; i < cnt; i += 512)
        atomicAdd(&hist[binned[base + i] >> 17], 1u);
    __syncthreads();

    unsigned int v = (tid < 128) ? hist[tid] : 0;
    unsigned int acc = v;
    if (tid < 128) sh[tid] = acc;
    __syncthreads();
    for (int o = 1; o < 128; o <<= 1) {
        unsigned int add = (tid >= o && tid < 128) ? sh[tid - o] : 0;
        __syncthreads();
        if (tid < 128) { acc += add; sh[tid] = acc; }
        __syncthreads();
    }
    if (tid < 128) {
        unsigned int exc = acc - v;
        rstart[tid] = exc;
        cur[tid] = exc;
    }
    __syncthreads();

    for (unsigned int i = tid; i < cnt; i += 512) {
        unsigned int e = binned[base + i];
        unsigned int p = atomicAdd(&cur[e >> 17], 1u);
        stg[p] = (e & 0x1FFFFu) * 192u;     // byte offset into kv table
    }
    __syncthreads();

    int wid = tid >> 6, lane = tid & 63;
    int hl   = lane & 31;          // v-pair owner: comps 2hl, 2hl+1
    int sub  = lane >> 5;          // which edge of the pair
    int head = hl >> 3;            // 0..3
    const char* kvb = (const char*)kv32;
    const char* qsb = (const char*)qs16;

    for (int nl = wid * 16; nl < wid * 16 + 16; ++nl) {
        int n = b * 128 + nl;
        if (n >= N) break;
        int dg = (int)hist[nl];
        if (dg == 0) {
            if (lane < 32)
                *reinterpret_cast<float2*>(&out[(size_t)n * 64 + 2 * hl]) =
                    make_float2(0.f, 0.f);
            continue;
        }
        int start = (int)rstart[nl];
        int last = start + dg - 1;
        float sc = 0.25f * rsqrtf((float)dg);

        uint4 q4 = *(const uint4*)(qsb + (size_t)n * 64 + (head << 4));
        float qf0 = bflo(q4.x) * sc, qf1 = bfhi(q4.x) * sc;
        float qf2 = bflo(q4.y) * sc, qf3 = bfhi(q4.y) * sc;
        float qf4 = bflo(q4.z) * sc, qf5 = bfhi(q4.z) * sc;
        float qf6 = bflo(q4.w) * sc, qf7 = bfhi(q4.w) * sc;

        float accx = 0.f, accy = 0.f, den = 0.f;
        int npairs = (dg + 1) >> 1;
        int idx = start + sub;

        unsigned int co = stg[min(idx, last)];
        float wm = (idx <= last) ? 1.f : 0.f;
        uint4 kr = *(const uint4*)(kvb + co + (head << 4));
        unsigned int vr = *(const unsigned int*)(kvb + co + 64 + (hl << 2));

        for (int i = 0; i < npairs; ++i) {
            uint4 kr2 = kr; unsigned int vr2 = vr; float wm2 = 0.f;
            int idx2 = idx + 2;
            if (i + 1 < npairs) {
                unsigned int co2 = stg[min(idx2, last)];
                wm2 = (idx2 <= last) ? 1.f : 0.f;
                kr2 = *(const uint4*)(kvb + co2 + (head << 4));
                vr2 = *(const unsigned int*)(kvb + co2 + 64 + (hl << 2));
            }
            float p = qf0 * bflo(kr.x);
            p = fmaf(qf1, bfhi(kr.x), p);
            p = fmaf(qf2, bflo(kr.y), p);
            p = fmaf(qf3, bfhi(kr.y), p);
            p = fmaf(qf4, bflo(kr.z), p);
            p = fmaf(qf5, bfhi(kr.z), p);
            p = fmaf(qf6, bflo(kr.w), p);
            p = fmaf(qf7, bfhi(kr.w), p);
            float w = __expf(p) * wm;
            accx = fmaf(w, bflo(vr), accx);
            accy = fmaf(w, bfhi(vr), accy);
            den += w;
            kr = kr2; vr = vr2; wm = wm2; idx = idx2;
        }

        accx += __shfl_xor(accx, 32);
        accy += __shfl_xor(accy, 32);
        den  += __shfl_xor(den, 32);

        if (lane < 32) {
            float inv = 1.0f / (den + 1e-16f);
            *reinterpret_cast<float2*>(&out[(size_t)n * 64 + 2 * hl]) =
                make_float2(accx * inv, accy * inv);
        }
    }
}

extern "C" void kernel_launch(void* const* d_in, const int* in_sizes, int n_in,
                              void* d_out, int out_size, void* d_ws, size_t ws_size,
                              hipStream_t stream) {
    const float* x = (const float*)d_in[0];
    const int*   eidx = (const int*)d_in[1];
    const float* W = (const float*)d_in[2];
    const float* b = (const float*)d_in[3];
    int N = in_sizes[0] / NDIM;
    int E = in_sizes[1] / 2;
    float* out = (float*)d_out;

    int NB = (N + 127) / 128;                  // 782 buckets
    int nbin = (E + CTILE - 1) / CTILE;        // 196 bin tiles

    // workspace layout
    unsigned short* qs16 = (unsigned short*)d_ws;                 // N*32 u16
    unsigned short* kv = qs16 + (size_t)N * 32;                   // N*96 u16
    unsigned int* gcur = (unsigned int*)(kv + (size_t)N * 96);    // NBMAX
    unsigned int* binned = gcur + NBMAX;       // NB*STGMAX u32 (~13.6 MB)

    const int* s_arr = eidx;
    const int* t_arr = eidx + E;

    hipMemsetAsync(gcur, 0, NBMAX * sizeof(unsigned int), stream);

    fused_bin_gemm_kernel<<<nbin + GEMM_BLKS, 1024, 0, stream>>>(
        s_arr, t_arr, gcur, binned, x, W, b, qs16, kv, N, E, nbin);
    sort_aggregate_kernel<<<NB, 512, 0, stream>>>(
        gcur, binned, qs16, (const unsigned int*)kv, out, N);
}